// Round 12
// baseline (5125.544 us; speedup 1.0000x reference)
//
#include <hip/hip_runtime.h>
#include <math.h>

#define BATCH 8
#define LSEQ 2048
#define DMODEL 512
#define TOPK 38
#define MROWS (BATCH * LSEQ) /* 16384 */
#define WSLOT (DMODEL * DMODEL) /* elements per weight slot */

typedef __attribute__((ext_vector_type(8))) short bf16x8;
typedef __attribute__((ext_vector_type(4))) float f32x4;

// ---------------------------------------------------------------------------
// utility
// ---------------------------------------------------------------------------
__device__ __forceinline__ float wave_sum(float v) {
#pragma unroll
  for (int off = 32; off > 0; off >>= 1) v += __shfl_down(v, off);
  return v;
}

__device__ __forceinline__ short f2bf(float f) {  // fp32 -> bf16 bits, RNE
  unsigned u = __float_as_uint(f);
  unsigned r = (u + 0x7fffu + ((u >> 16) & 1u)) >> 16;
  return (short)r;
}

// ---------------------------------------------------------------------------
// tables: temporal-embed rows 0..6 and FFT twiddles e^{-2pi i m/2048}, m<1024
// ---------------------------------------------------------------------------
__global__ void table_init_kernel(float* __restrict__ tab, float2* __restrict__ twg) {
  int i = blockIdx.x * 256 + threadIdx.x;
  if (i < 7 * DMODEL) {
    int p = i >> 9;
    int d = i & (DMODEL - 1);
    float div = expf((float)(d >> 1) * (-2.0f * 9.210340371976184f / 512.0f)); // ln(10000)
    float ang = (float)p * div;
    tab[i] = (d & 1) ? cosf(ang) : sinf(ang);
  }
  if (i < 1024) {
    float ang = -6.283185307179586f * (float)i / 2048.0f;
    float sn, cs;
    sincosf(ang, &sn, &cs);
    twg[i] = make_float2(cs, sn);
  }
}

// ---------------------------------------------------------------------------
// embedding: out[b,t,d] = circ_conv3(x(7ch)) + sum of 4 temporal table rows
// ---------------------------------------------------------------------------
__global__ __launch_bounds__(256) void embed_kernel(
    const float* __restrict__ x,    // (B,L,7)
    const float* __restrict__ W,    // (3,7,512)
    const int* __restrict__ mark,   // (B,L,4)
    const float* __restrict__ tab,  // (7,512)
    float* __restrict__ out)        // (B,L,512)
{
  __shared__ float xs[21];
  int bt = blockIdx.x;
  int b = bt >> 11, t = bt & (LSEQ - 1);
  int tid = threadIdx.x;
  if (tid < 21) {
    int j = tid / 7, c = tid - j * 7;
    int row = (t - 1 + j + LSEQ) & (LSEQ - 1);
    xs[tid] = x[((size_t)b * LSEQ + row) * 7 + c];
  }
  __syncthreads();
  const int* mk = mark + ((size_t)b * LSEQ + t) * 4;
  int m0 = mk[0], m1 = mk[1], m2 = mk[2], m3 = mk[3];
#pragma unroll
  for (int h = 0; h < 2; ++h) {
    int d = tid + h * 256;
    float acc = tab[m0 * DMODEL + d] + tab[m1 * DMODEL + d] +
                tab[m2 * DMODEL + d] + tab[m3 * DMODEL + d];
#pragma unroll
    for (int j = 0; j < 3; ++j)
#pragma unroll
      for (int c = 0; c < 7; ++c)
        acc += xs[j * 7 + c] * W[(size_t)((j * 7 + c) * DMODEL) + d];
    out[((size_t)b * LSEQ + t) * DMODEL + d] = acc;
  }
}

// ---------------------------------------------------------------------------
// series_decomp D=7 (phase 0 only): seasonal = x - movavg25, trend write
// ---------------------------------------------------------------------------
__global__ void decomp7_kernel(const float* __restrict__ x, float* __restrict__ seas,
                               float* __restrict__ trend)
{
  int bt = blockIdx.x;
  int b = bt >> 11, t = bt & (LSEQ - 1);
  const float* xb = x + (size_t)b * LSEQ * 7;
  for (int d = threadIdx.x; d < 7; d += blockDim.x) {
    float s = 0.f;
#pragma unroll
    for (int o = -12; o <= 12; ++o) {
      int tt = t + o;
      tt = tt < 0 ? 0 : (tt > LSEQ - 1 ? LSEQ - 1 : tt);
      s += xb[(size_t)tt * 7 + d];
    }
    float mov = s / 25.0f;
    size_t idx = ((size_t)b * LSEQ + t) * 7 + d;
    seas[idx] = x[idx] - mov;
    trend[idx] = mov;
  }
}

// ---------------------------------------------------------------------------
// series_decomp D=512, LDS-tiled: identical 25-term ascending sum, staged in
// LDS (56-row x 256-col tile) so each input is read once from global.
// Bit-identical to the naive version (same values, same add order).
// ---------------------------------------------------------------------------
__global__ __launch_bounds__(256) void decomp512_kernel(
    const float* __restrict__ x, float* __restrict__ seas,
    float* __restrict__ trend, int mode)
{
  __shared__ float ls[56][256];
  int tc = blockIdx.x;   // t-chunk of 32: 0..63
  int b = blockIdx.y;    // 0..7
  int dh = blockIdx.z;   // d-half: 0..1
  int tid = threadIdx.x;
  int d = dh * 256 + tid;
  const float* xb = x + (size_t)b * LSEQ * DMODEL;
  int t0 = tc * 32;
#pragma unroll 1
  for (int r = 0; r < 56; ++r) {
    int tg = t0 - 12 + r;
    tg = tg < 0 ? 0 : (tg > LSEQ - 1 ? LSEQ - 1 : tg);
    ls[r][tid] = xb[(size_t)tg * DMODEL + d];
  }
  __syncthreads();
#pragma unroll 1
  for (int tl = 0; tl < 32; ++tl) {
    float s = 0.f;
#pragma unroll
    for (int o = -12; o <= 12; ++o) s += ls[tl + 12 + o][tid];
    float mov = s / 25.0f;
    size_t idx = ((size_t)b * LSEQ + t0 + tl) * DMODEL + d;
    seas[idx] = ls[tl + 12][tid] - mov;
    if (mode == 1) trend[idx] = mov;
    else if (mode == 2) trend[idx] += mov;
  }
}

// ---------------------------------------------------------------------------
// fp32 SGEMM (Q/K projections — precision-critical top-k path).
// 64x128 tile (M x N), BK=16, 256 thr, grid 1024 blocks (4/CU) for occupancy.
// Accumulation order per output identical to previous version (k ascending).
// ---------------------------------------------------------------------------
__global__ __launch_bounds__(256) void sgemm_kernel(
    const float* __restrict__ A, const float* __restrict__ B,
    const float* __restrict__ bias, float* __restrict__ C,
    int M, int N, int K)
{
  __shared__ float As[16][68];   // [k][m], pad 68 (16B-aligned rows)
  __shared__ float Bs[16][132];  // [k][n]
  int m0 = blockIdx.x * 64;
  int n0 = blockIdx.y * 128;
  int tid = threadIdx.x;
  int tx = tid & 15, ty = tid >> 4;  // n-frag, m-frag
  float acc[4][8];
#pragma unroll
  for (int i = 0; i < 4; ++i)
#pragma unroll
    for (int j = 0; j < 8; ++j) acc[i][j] = 0.f;

  int ar = tid >> 2;        // 0..63 (m)
  int ac = (tid & 3) << 2;  // 0,4,8,12 (k)
  int br = tid >> 5;        // 0..7 (k)
  int bc = (tid & 31) << 2; // 0..124 (n)

  for (int k0 = 0; k0 < K; k0 += 16) {
    float4 a0 = *(const float4*)(A + (size_t)(m0 + ar) * K + k0 + ac);
    float4 b0 = *(const float4*)(B + (size_t)(k0 + br) * N + n0 + bc);
    float4 b1 = *(const float4*)(B + (size_t)(k0 + 8 + br) * N + n0 + bc);
    As[ac + 0][ar] = a0.x; As[ac + 1][ar] = a0.y; As[ac + 2][ar] = a0.z; As[ac + 3][ar] = a0.w;
    *(float4*)&Bs[br][bc] = b0;
    *(float4*)&Bs[br + 8][bc] = b1;
    __syncthreads();
#pragma unroll
    for (int k = 0; k < 16; ++k) {
      float av[4], bv[8];
      *(float4*)(av)     = *(const float4*)&As[k][ty * 4];
      *(float4*)(bv)     = *(const float4*)&Bs[k][tx * 8];
      *(float4*)(bv + 4) = *(const float4*)&Bs[k][tx * 8 + 4];
#pragma unroll
      for (int i = 0; i < 4; ++i)
#pragma unroll
        for (int j = 0; j < 8; ++j)
          acc[i][j] = fmaf(av[i], bv[j], acc[i][j]);
    }
    __syncthreads();
  }
#pragma unroll
  for (int i = 0; i < 4; ++i) {
    int m = m0 + ty * 4 + i;
    float* cr = C + (size_t)m * N + n0 + tx * 8;
#pragma unroll
    for (int j = 0; j < 8; j += 4) {
      float4 v = make_float4(acc[i][j], acc[i][j + 1], acc[i][j + 2], acc[i][j + 3]);
      if (bias) {
        const float* bp = bias + n0 + tx * 8 + j;
        v.x += bp[0]; v.y += bp[1]; v.z += bp[2]; v.w += bp[3];
      }
      *(float4*)(cr + j) = v;
    }
  }
}

// ---------------------------------------------------------------------------
// weight prep (batched): W fp32 (nl,512,512) -> Wt bf16 (nl,512t,512)
// grid z = layer. Identical per-element conversion as before.
// ---------------------------------------------------------------------------
__global__ void prep_wt_multi_kernel(const float* __restrict__ W, short* __restrict__ Wt) {
  __shared__ float tile[32][33];
  int layer = blockIdx.z;
  const float* src = W + (size_t)layer * WSLOT;
  short* dst = Wt + (size_t)layer * WSLOT;
  int k0 = blockIdx.x << 5, n0 = blockIdx.y << 5;
  for (int i = threadIdx.y; i < 32; i += 8)
    tile[i][threadIdx.x] = src[(size_t)(k0 + i) * DMODEL + n0 + threadIdx.x];
  __syncthreads();
  for (int i = threadIdx.y; i < 32; i += 8)
    dst[(size_t)(n0 + i) * DMODEL + k0 + threadIdx.x] = f2bf(tile[threadIdx.x][i]);
}

// ---------------------------------------------------------------------------
// bf16 MFMA GEMM (V/O/FFN — precision-tolerant paths):
// C(M,512) = A(M,512) @ W(512,512) (+bias), Wt[n][k] bf16. 128x128, BK=32.
// ---------------------------------------------------------------------------
__global__ __launch_bounds__(256) void gemm_bf16_kernel(
    const float* __restrict__ A, const short* __restrict__ Wt,
    const float* __restrict__ bias, float* __restrict__ C)
{
  const int K = DMODEL, N = DMODEL;
  __shared__ short As[128][40];  // [m][k] bf16, pad 40 (80B rows, 16B aligned)
  __shared__ short Bs[128][40];  // [n][k] bf16
  int m0 = blockIdx.x * 128;
  int n0 = blockIdx.y * 128;
  int tid = threadIdx.x;
  int lane = tid & 63;
  int wave = tid >> 6;
  int wm = (wave >> 1) * 64;
  int wn = (wave & 1) * 64;
  int lr = lane & 15;         // fragment row (A) / col (B) / out col
  int lk = (lane >> 4) * 8;   // fragment k-offset

  f32x4 acc[4][4];
#pragma unroll
  for (int i = 0; i < 4; ++i)
#pragma unroll
    for (int j = 0; j < 4; ++j) acc[i][j] = (f32x4){0.f, 0.f, 0.f, 0.f};

  for (int k0 = 0; k0 < K; k0 += 32) {
    // stage A: 128x32 fp32 -> bf16 (1024 float4, 4 per thread)
#pragma unroll
    for (int i = 0; i < 4; ++i) {
      int f = tid + i * 256;
      int row = f >> 3, c4 = (f & 7) << 2;
      float4 v = *(const float4*)(A + (size_t)(m0 + row) * K + k0 + c4);
      short4 s = make_short4(f2bf(v.x), f2bf(v.y), f2bf(v.z), f2bf(v.w));
      *(short4*)&As[row][c4] = s;
    }
    // stage B: 128x32 bf16 copy (512 x 16B, 2 per thread)
#pragma unroll
    for (int i = 0; i < 2; ++i) {
      int f = tid + i * 256;
      int row = f >> 2, c8 = (f & 3) << 3;
      *(int4*)&Bs[row][c8] = *(const int4*)(Wt + (size_t)(n0 + row) * K + k0 + c8);
    }
    __syncthreads();
    bf16x8 af[4], bfr[4];
#pragma unroll
    for (int m = 0; m < 4; ++m) af[m] = *(const bf16x8*)&As[wm + m * 16 + lr][lk];
#pragma unroll
    for (int n = 0; n < 4; ++n) bfr[n] = *(const bf16x8*)&Bs[wn + n * 16 + lr][lk];
#pragma unroll
    for (int m = 0; m < 4; ++m)
#pragma unroll
      for (int n = 0; n < 4; ++n)
        acc[m][n] = __builtin_amdgcn_mfma_f32_16x16x32_bf16(af[m], bfr[n], acc[m][n], 0, 0, 0);
    __syncthreads();
  }
  // epilogue: D lane mapping col = lane&15, row = (lane>>4)*4 + reg
  int orow = m0 + wm + (lane >> 4) * 4;
  int ocol = n0 + wn + lr;
#pragma unroll
  for (int m = 0; m < 4; ++m)
#pragma unroll
    for (int n = 0; n < 4; ++n) {
      int col = ocol + n * 16;
      float bv = bias ? bias[col] : 0.f;
#pragma unroll
      for (int r = 0; r < 4; ++r)
        C[(size_t)(orow + m * 16 + r) * N + col] = acc[m][n][r] + bv;
    }
}

// ---------------------------------------------------------------------------
// transpose (B,2048,512) -> (B,512,2048)
// ---------------------------------------------------------------------------
__global__ void transpose_kernel(const float* __restrict__ in, float* __restrict__ out) {
  __shared__ float tile[32][33];
  int b = blockIdx.x;
  int r0 = blockIdx.y << 5;
  int c0 = blockIdx.z << 5;
  const float* ib = in + (size_t)b * LSEQ * DMODEL;
  float* ob = out + (size_t)b * LSEQ * DMODEL;
  for (int i = threadIdx.y; i < 32; i += 8)
    tile[i][threadIdx.x] = ib[(size_t)(r0 + i) * DMODEL + c0 + threadIdx.x];
  __syncthreads();
  for (int i = threadIdx.y; i < 32; i += 8)
    ob[(size_t)(c0 + i) * LSEQ + r0 + threadIdx.x] = tile[threadIdx.x][i];
}

// ---------------------------------------------------------------------------
// in-place radix-2 DIT FFT, 2048 pts, input pre-bit-reversed, 256 threads
// ---------------------------------------------------------------------------
__device__ __forceinline__ void fft2048_lds(float2* buf, const float2* tw, int tid, int inverse) {
#pragma unroll 1
  for (int s = 1; s <= 11; ++s) {
    int half = 1 << (s - 1);
#pragma unroll 1
    for (int bf = tid; bf < 1024; bf += 256) {
      int j = bf & (half - 1);
      int i0 = ((bf >> (s - 1)) << s) | j;
      int i1 = i0 + half;
      float2 w = tw[j << (11 - s)];
      float wy = inverse ? -w.y : w.y;
      float2 a = buf[i0], b = buf[i1];
      float tr = b.x * w.x - b.y * wy;
      float ti = b.x * wy + b.y * w.x;
      buf[i0] = make_float2(a.x + tr, a.y + ti);
      buf[i1] = make_float2(a.x - tr, a.y - ti);
    }
    __syncthreads();
  }
}

// ---------------------------------------------------------------------------
// packed q+ik FFT per channel, accumulate product spectrum over 8 channels
// per block; 64 blocks per batch -> partial[b*64+g][f]
// ---------------------------------------------------------------------------
__global__ __launch_bounds__(256) void corr_spectrum_kernel(
    const float* __restrict__ qt, const float* __restrict__ kt,  // (B,512,2048)
    const float2* __restrict__ twg, float2* __restrict__ partial)
{
  __shared__ float2 buf[2048];
  __shared__ float2 acc[2048];
  __shared__ float2 twl[1024];
  int tid = threadIdx.x;
  int b = blockIdx.x >> 6;
  int g = blockIdx.x & 63;
  for (int i = tid; i < 1024; i += 256) twl[i] = twg[i];
  for (int i = tid; i < 2048; i += 256) acc[i] = make_float2(0.f, 0.f);
  __syncthreads();
#pragma unroll 1
  for (int ch = 0; ch < 8; ++ch) {
    int d = (g << 3) + ch;
    const float* qr = qt + ((size_t)b * DMODEL + d) * LSEQ;
    const float* kr = kt + ((size_t)b * DMODEL + d) * LSEQ;
    for (int i = tid; i < 2048; i += 256) {
      int rev = __brev((unsigned)i) >> 21;
      buf[rev] = make_float2(qr[i], kr[i]);
    }
    __syncthreads();
    fft2048_lds(buf, twl, tid, 0);
    for (int i = tid; i < 2048; i += 256) {
      float2 z1 = buf[i];
      float2 z2 = buf[(2048 - i) & 2047];
      float Qr = 0.5f * (z1.x + z2.x);
      float Qi = 0.5f * (z1.y - z2.y);
      float Kr = 0.5f * (z1.y + z2.y);
      float Ki = -0.5f * (z1.x - z2.x);
      acc[i].x += Qr * Kr + Qi * Ki;   // Q * conj(K)
      acc[i].y += Qi * Kr - Qr * Ki;
    }
    __syncthreads();
  }
  float2* op = partial + (size_t)blockIdx.x * 2048;
  for (int i = tid; i < 2048; i += 256) op[i] = acc[i];
}

// many-block reduction of the 64 partial spectra per batch -> spec[b][2048]
__global__ __launch_bounds__(256) void reduce_partials_kernel(
    const float2* __restrict__ partial, float2* __restrict__ spec)
{
  int b = blockIdx.x;
  int i = blockIdx.y * 256 + threadIdx.x;
  const float2* pp = partial + ((size_t)b * 64) * 2048 + i;
  float sx = 0.f, sy = 0.f;
#pragma unroll 8
  for (int g = 0; g < 64; ++g) {
    float2 v = pp[(size_t)g * 2048];
    sx += v.x; sy += v.y;
  }
  spec[(size_t)b * 2048 + i] = make_float2(sx, sy);
}

// inverse FFT of summed spectrum -> mean_value (B,2048)
__global__ __launch_bounds__(256) void ifft_kernel(
    const float2* __restrict__ spec, const float2* __restrict__ twg,
    float* __restrict__ mv)
{
  __shared__ float2 buf[2048];
  __shared__ float2 twl[1024];
  int tid = threadIdx.x;
  int b = blockIdx.x;
  for (int i = tid; i < 1024; i += 256) twl[i] = twg[i];
  for (int i = tid; i < 2048; i += 256) {
    int rev = __brev((unsigned)i) >> 21;
    buf[rev] = spec[(size_t)b * 2048 + i];
  }
  __syncthreads();
  fft2048_lds(buf, twl, tid, 1);
  const float scale = 1.0f / (2048.0f * 512.0f);  // 1/L (irfft) * 1/(H*E) (mean)
  for (int i = tid; i < 2048; i += 256) mv[(size_t)b * 2048 + i] = buf[i].x * scale;
}

// top-38 of batch-summed mean_value, then per-batch softmax weights
__global__ void topk_kernel(const float* __restrict__ mv, int* __restrict__ idxOut,
                            float* __restrict__ wOut)
{
  __shared__ float cm[2048];
  __shared__ float rmax[256];
  __shared__ int rIdx[256];
  __shared__ int sIdx[TOPK];
  int tid = threadIdx.x;
  for (int i = tid; i < 2048; i += 256) {
    float s = 0.f;
#pragma unroll
    for (int b = 0; b < BATCH; ++b) s += mv[(size_t)b * 2048 + i];
    cm[i] = s;
  }
  __syncthreads();
  for (int it = 0; it < TOPK; ++it) {
    float best = -1e30f; int bi = 0;
    for (int i = tid; i < 2048; i += 256)
      if (cm[i] > best) { best = cm[i]; bi = i; }
    rmax[tid] = best; rIdx[tid] = bi;
    __syncthreads();
    for (int s = 128; s > 0; s >>= 1) {
      if (tid < s && rmax[tid + s] > rmax[tid]) { rmax[tid] = rmax[tid + s]; rIdx[tid] = rIdx[tid + s]; }
      __syncthreads();
    }
    if (tid == 0) { sIdx[it] = rIdx[0]; idxOut[it] = rIdx[0]; cm[rIdx[0]] = -1e30f; }
    __syncthreads();
  }
  if (tid < BATCH) {
    int b = tid;
    float vals[TOPK];
    float m = -1e30f;
    for (int j = 0; j < TOPK; ++j) { vals[j] = mv[(size_t)b * 2048 + sIdx[j]]; m = fmaxf(m, vals[j]); }
    float s = 0.f;
    for (int j = 0; j < TOPK; ++j) { vals[j] = expf(vals[j] - m); s += vals[j]; }
    for (int j = 0; j < TOPK; ++j) wOut[b * TOPK + j] = vals[j] / s;
  }
}

// out[b,t,d] = sum_j w[b,j] * v[b,(t+idx_j)%L,d]
// block -> (b = bid&7) so each XCD's L2 caches exactly one batch's V (4MB)
__global__ __launch_bounds__(256) void shift_sum_kernel(
    const float* __restrict__ v, const int* __restrict__ idx,
    const float* __restrict__ w, float* __restrict__ out)
{
  __shared__ int sidx[TOPK];
  __shared__ float sw[TOPK];
  int bt = blockIdx.x;
  int b = bt & 7, t = bt >> 3;
  int tid = threadIdx.x;
  if (tid < TOPK) { sidx[tid] = idx[tid]; sw[tid] = w[b * TOPK + tid]; }
  __syncthreads();
  float a0 = 0.f, a1 = 0.f;
  const float* vb = v + (size_t)b * LSEQ * DMODEL;
#pragma unroll 1
  for (int j = 0; j < TOPK; ++j) {
    int row = (t + sidx[j]) & (LSEQ - 1);
    const float* vr = vb + (size_t)row * DMODEL;
    a0 = fmaf(sw[j], vr[tid], a0);
    a1 = fmaf(sw[j], vr[tid + 256], a1);
  }
  size_t o = ((size_t)b * LSEQ + t) * DMODEL;
  out[o + tid] = a0;
  out[o + tid + 256] = a1;
}

// ---------------------------------------------------------------------------
// elementwise
// ---------------------------------------------------------------------------
__global__ void add_kernel(const float* __restrict__ a, const float* __restrict__ b,
                           float* __restrict__ c, int n4)
{
  int i = blockIdx.x * blockDim.x + threadIdx.x;
  int stride = gridDim.x * blockDim.x;
  const float4* A = (const float4*)a;
  const float4* B = (const float4*)b;
  float4* C = (float4*)c;
  for (; i < n4; i += stride) {
    float4 x = A[i], y = B[i];
    C[i] = make_float4(x.x + y.x, x.y + y.y, x.z + y.z, x.w + y.w);
  }
}

__global__ void gelu_kernel(float* __restrict__ x, int n4) {
  int i = blockIdx.x * blockDim.x + threadIdx.x;
  int stride = gridDim.x * blockDim.x;
  float4* X = (float4*)x;
  const float k = 0.7071067811865475f;
  for (; i < n4; i += stride) {
    float4 v = X[i];
    v.x = 0.5f * v.x * (1.f + erff(v.x * k));
    v.y = 0.5f * v.y * (1.f + erff(v.y * k));
    v.z = 0.5f * v.z * (1.f + erff(v.z * k));
    v.w = 0.5f * v.w * (1.f + erff(v.w * k));
    X[i] = v;
  }
}

// row layernorm over 512 (eps 1e-5)
__global__ __launch_bounds__(256) void layernorm_kernel(
    const float* __restrict__ x, const float* __restrict__ w,
    const float* __restrict__ bb, float* __restrict__ out)
{
  __shared__ float red[256];
  int row = blockIdx.x;
  int tid = threadIdx.x;
  const float* xr = x + (size_t)row * DMODEL;
  float v0 = xr[tid], v1 = xr[tid + 256];
  red[tid] = v0 + v1;
  __syncthreads();
  for (int o = 128; o > 0; o >>= 1) {
    if (tid < o) red[tid] += red[tid + o];
    __syncthreads();
  }
  float mu = red[0] / 512.0f;
  __syncthreads();
  float d0 = v0 - mu, d1 = v1 - mu;
  red[tid] = d0 * d0 + d1 * d1;
  __syncthreads();
  for (int o = 128; o > 0; o >>= 1) {
    if (tid < o) red[tid] += red[tid + o];
    __syncthreads();
  }
  float var = red[0] / 512.0f;
  float inv = 1.0f / sqrtf(var + 1e-5f);
  out[(size_t)row * DMODEL + tid] = d0 * inv * w[tid] + bb[tid];
  out[(size_t)row * DMODEL + tid + 256] = d1 * inv * w[tid + 256] + bb[tid + 256];
}

// column (time-axis) mean subtraction: 3 stages
__global__ __launch_bounds__(256) void colsum_kernel(const float* __restrict__ x,
                                                     float* __restrict__ part)
{
  int b = blockIdx.x, ch = blockIdx.y;
  const float* xb = x + ((size_t)b * LSEQ + (size_t)ch * 128) * DMODEL;
  float s0 = 0.f, s1 = 0.f;
#pragma unroll 1
  for (int t = 0; t < 128; ++t) {
    s0 += xb[(size_t)t * DMODEL + threadIdx.x];
    s1 += xb[(size_t)t * DMODEL + threadIdx.x + 256];
  }
  part[(size_t)(b * 16 + ch) * DMODEL + threadIdx.x] = s0;
  part[(size_t)(b * 16 + ch) * DMODEL + threadIdx.x + 256] = s1;
}

__global__ void colmean_finish_kernel(const float* __restrict__ part, float* __restrict__ mu) {
  int i = blockIdx.x * 256 + threadIdx.x;
  if (i < BATCH * DMODEL) {
    int b = i / DMODEL, d = i - b * DMODEL;
    float s = 0.f;
#pragma unroll
    for (int c = 0; c < 16; ++c) s += part[(size_t)(b * 16 + c) * DMODEL + d];
    mu[i] = s / (float)LSEQ;
  }
}

__global__ __launch_bounds__(256) void sub_colmean_kernel(
    const float* __restrict__ x, const float* __restrict__ mu, float* __restrict__ out)
{
  int bt = blockIdx.x;
  int b = bt >> 11;
  size_t base = (size_t)bt * DMODEL;
  int d0 = threadIdx.x, d1 = threadIdx.x + 256;
  out[base + d0] = x[base + d0] - mu[b * DMODEL + d0];
  out[base + d1] = x[base + d1] - mu[b * DMODEL + d1];
}

// ---------------------------------------------------------------------------
// small kernels
// ---------------------------------------------------------------------------
__global__ void mean_enc_kernel(const float* __restrict__ x, float* __restrict__ mean7) {
  int b = blockIdx.x / 7, c = blockIdx.x % 7;
  float s = 0.f;
  for (int t = threadIdx.x; t < LSEQ; t += 64) s += x[((size_t)b * LSEQ + t) * 7 + c];
  s = wave_sum(s);
  if (threadIdx.x == 0) mean7[b * 7 + c] = s / 2048.0f;
}

__global__ void build_inits_kernel(const float* __restrict__ seas7, const float* __restrict__ trend7,
                                   const float* __restrict__ mean7,
                                   float* __restrict__ seasonal_init, float* __restrict__ trend_acc)
{
  int i = blockIdx.x * 256 + threadIdx.x;
  if (i >= BATCH * LSEQ * 7) return;
  int c = i % 7;
  int bt = i / 7;
  int t = bt & (LSEQ - 1);
  int b = bt >> 11;
  if (t < 1024) {
    size_t src = ((size_t)b * LSEQ + (t + 1024)) * 7 + c;
    seasonal_init[i] = seas7[src];
    trend_acc[i] = trend7[src];
  } else {
    seasonal_init[i] = 0.f;
    trend_acc[i] = mean7[b * 7 + c];
  }
}

// trend += circ_conv3(x(512ch), W(3,512,7)); one wave per (b,t)
__global__ void trend_conv_kernel(const float* __restrict__ x, const float* __restrict__ W,
                                  float* __restrict__ trend)
{
  int bt = blockIdx.x;
  int b = bt >> 11, t = bt & (LSEQ - 1);
  int lane = threadIdx.x;
  float acc[7] = {0, 0, 0, 0, 0, 0, 0};
#pragma unroll
  for (int j = 0; j < 3; ++j) {
    int row = (t - 1 + j + LSEQ) & (LSEQ - 1);
    const float* xr = x + ((size_t)b * LSEQ + row) * DMODEL;
    const float* wj = W + (size_t)j * DMODEL * 7;
    for (int d = lane; d < DMODEL; d += 64) {
      float xv = xr[d];
      const float* wr = wj + d * 7;
#pragma unroll
      for (int c = 0; c < 7; ++c) acc[c] += xv * wr[c];
    }
  }
#pragma unroll
  for (int c = 0; c < 7; ++c) {
    float s = wave_sum(acc[c]);
    if (lane == 0) trend[((size_t)b * LSEQ + t) * 7 + c] += s;
  }
}

// final: d_out[b,tt,c] = trend[b,1024+tt,c] + x[b,1024+tt,:] @ projW + projb
__global__ void final_proj_kernel(const float* __restrict__ x, const float* __restrict__ W,
                                  const float* __restrict__ bias, const float* __restrict__ trend,
                                  float* __restrict__ out)
{
  int bt = blockIdx.x;
  int b = bt >> 10, tt = bt & 1023;
  int t = tt + 1024;
  int lane = threadIdx.x;
  const float* xr = x + ((size_t)b * LSEQ + t) * DMODEL;
  float acc[7] = {0, 0, 0, 0, 0, 0, 0};
  for (int d = lane; d < DMODEL; d += 64) {
    float xv = xr[d];
    const float* wr = W + d * 7;
#pragma unroll
    for (int c = 0; c < 7; ++c) acc[c] += xv * wr[c];
  }
#pragma unroll
  for (int c = 0; c < 7; ++c) {
    float s = wave_sum(acc[c]);
    if (lane == 0)
      out[((size_t)b * 1024 + tt) * 7 + c] = s + bias[c] + trend[((size_t)b * LSEQ + t) * 7 + c];
  }
}

// ---------------------------------------------------------------------------
// host orchestration
// ---------------------------------------------------------------------------
static inline void launch_sgemm(const float* A, const float* W, const float* bias, float* C,
                                hipStream_t s)
{
  sgemm_kernel<<<dim3(MROWS / 64, DMODEL / 128), dim3(256), 0, s>>>(
      A, W, bias, C, MROWS, DMODEL, DMODEL);
}

static inline void launch_gemm_bf16(const float* A, const short* Wt, const float* bias, float* C,
                                    hipStream_t s)
{
  gemm_bf16_kernel<<<dim3(MROWS / 128, DMODEL / 128), dim3(256), 0, s>>>(A, Wt, bias, C);
}

static inline void launch_decomp512(const float* x, float* seas, float* trend, int mode,
                                    hipStream_t s)
{
  decomp512_kernel<<<dim3(64, BATCH, 2), dim3(256), 0, s>>>(x, seas, trend, mode);
}

struct AttnScratch {
  float2* partial;
  float2* spec;
  float* mv;
  int* idx;
  float* w;
  const float2* twg;
};

// t1,t2,t3 are 33.5MB temps; t3 receives the attention output.
// qx must be distinct from t1..t3; kx/vx are only read before t1 is rewritten.
// Q/K: fp32 SGEMM (feeds FFT->top-k index selection — precision-critical).
// V/O: bf16 MFMA with precomputed transposed weights.
static void run_attn(const float* qx, const float* kx, const float* vx,
                     const float* Wq, const float* bq, const float* Wk, const float* bk,
                     const short* wtV, const float* bv, const short* wtO, const float* bo,
                     float* t1, float* t2, float* t3, const AttnScratch& sc, hipStream_t s)
{
  dim3 tg(BATCH, LSEQ / 32, DMODEL / 32);
  launch_sgemm(qx, Wq, bq, t1, s);
  transpose_kernel<<<tg, dim3(32, 8), 0, s>>>(t1, t2);             // t2 = q^T
  launch_sgemm(kx, Wk, bk, t1, s);
  transpose_kernel<<<tg, dim3(32, 8), 0, s>>>(t1, t3);             // t3 = k^T
  launch_gemm_bf16(vx, wtV, bv, t1, s);                            // t1 = v
  corr_spectrum_kernel<<<dim3(BATCH * 64), dim3(256), 0, s>>>(t2, t3, sc.twg, sc.partial);
  reduce_partials_kernel<<<dim3(BATCH, 8), dim3(256), 0, s>>>(sc.partial, sc.spec);
  ifft_kernel<<<dim3(BATCH), dim3(256), 0, s>>>(sc.spec, sc.twg, sc.mv);
  topk_kernel<<<dim3(1), dim3(256), 0, s>>>(sc.mv, sc.idx, sc.w);
  shift_sum_kernel<<<dim3(MROWS), dim3(256), 0, s>>>(t1, sc.idx, sc.w, t2);  // t2 = agg
  launch_gemm_bf16(t2, wtO, bo, t3, s);                            // t3 = attn out
}

extern "C" void kernel_launch(void* const* d_in, const int* in_sizes, int n_in,
                              void* d_out, int out_size, void* d_ws, size_t ws_size,
                              hipStream_t stream)
{
  if (n_in < 41) return;  // defensive: unexpected harness input layout

  const float* x_enc    = (const float*)d_in[0];
  const int*   mark_enc = (const int*)d_in[1];
  const int*   mark_dec = (const int*)d_in[3];
  const float* emb_enc_W = (const float*)d_in[4];
  const float* emb_dec_W = (const float*)d_in[5];
  const float* enc_Wq = (const float*)d_in[6];
  const float* enc_bq = (const float*)d_in[7];
  const float* dec_sWq = (const float*)d_in[8];
  const float* dec_sbq = (const float*)d_in[9];
  const float* dec_cWq = (const float*)d_in[10];
  const float* dec_cbq = (const float*)d_in[11];
  const float* enc_Wk = (const float*)d_in[12];
  const float* enc_bk = (const float*)d_in[13];
  const float* dec_sWk = (const float*)d_in[14];
  const float* dec_sbk = (const float*)d_in[15];
  const float* dec_cWk = (const float*)d_in[16];
  const float* dec_cbk = (const float*)d_in[17];
  const float* enc_Wv = (const float*)d_in[18];
  const float* enc_bv = (const float*)d_in[19];
  const float* dec_sWv = (const float*)d_in[20];
  const float* dec_sbv = (const float*)d_in[21];
  const float* dec_cWv = (const float*)d_in[22];
  const float* dec_cbv = (const float*)d_in[23];
  const float* enc_Wo = (const float*)d_in[24];
  const float* enc_bo = (const float*)d_in[25];
  const float* dec_sWo = (const float*)d_in[26];
  const float* dec_sbo = (const float*)d_in[27];
  const float* dec_cWo = (const float*)d_in[28];
  const float* dec_cbo = (const float*)d_in[29];
  const float* enc_c1 = (const float*)d_in[30];
  const float* enc_c2 = (const float*)d_in[31];
  const float* enc_nw = (const float*)d_in[32];
  const float* enc_nb = (const float*)d_in[33];
  const float* dec_c1 = (const float*)d_in[34];
  const float* dec_c2 = (const float*)d_in[35];
  const float* dec_trendW = (const float*)d_in[36];
  const float* dec_nw = (const float*)d_in[37];
  const float* dec_nb = (const float*)d_in[38];
  const float* proj_W = (const float*)d_in[39];
  const float* proj_b = (const float*)d_in[40];

  (void)in_sizes; (void)out_size;

  // ----- workspace carve (~225 MB) -----
  const size_t BIG = (size_t)MROWS * DMODEL * sizeof(float);  // 33.55 MB
  char* p = (char*)d_ws;
  float* enc_out = (float*)p; p += BIG;
  float* dec_out = (float*)p; p += BIG;
  float* tsum    = (float*)p; p += BIG;
  float* b1 = (float*)p; p += BIG;
  float* b2 = (float*)p; p += BIG;
  float* b3 = (float*)p; p += BIG;
  float2* partial = (float2*)p; p += (size_t)BATCH * 64 * 2048 * sizeof(float2);
  float2* specbuf = (float2*)p; p += (size_t)BATCH * 2048 * sizeof(float2);
  short* wtAll = (short*)p; p += (size_t)24 * WSLOT * sizeof(short);  // 12.58 MB
  float* mv = (float*)p; p += (size_t)BATCH * 2048 * sizeof(float);
  float* tab = (float*)p; p += 7 * DMODEL * sizeof(float);
  float2* twg = (float2*)p; p += 1024 * sizeof(float2);
  float* seas7 = (float*)p; p += (size_t)BATCH * LSEQ * 7 * sizeof(float);
  float* trend7tmp = (float*)p; p += (size_t)BATCH * LSEQ * 7 * sizeof(float);
  float* seasonal_init = (float*)p; p += (size_t)BATCH * LSEQ * 7 * sizeof(float);
  float* trend_acc = (float*)p; p += (size_t)BATCH * LSEQ * 7 * sizeof(float);
  float* colpart = (float*)p; p += (size_t)BATCH * 16 * DMODEL * sizeof(float);
  float* colmu = (float*)p; p += (size_t)BATCH * DMODEL * sizeof(float);
  float* mean7 = (float*)p; p += 256;
  int* idxbuf = (int*)p; p += 256;
  float* wbuf = (float*)p; p += 2048;
  if ((size_t)(p - (char*)d_ws) > ws_size) return;  // insufficient scratch

  const int n4 = MROWS * DMODEL / 4;
  AttnScratch sc{partial, specbuf, mv, idxbuf, wbuf, twg};

  // bf16 weight slots (precomputed once): index in units of WSLOT
  short* wt_enc_Wv = wtAll + (size_t)0 * WSLOT;   // 3 layers
  short* wt_enc_Wo = wtAll + (size_t)3 * WSLOT;   // 3
  short* wt_enc_c1 = wtAll + (size_t)6 * WSLOT;   // 3
  short* wt_enc_c2 = wtAll + (size_t)9 * WSLOT;   // 3
  short* wt_dec_sWv = wtAll + (size_t)12 * WSLOT; // 2
  short* wt_dec_sWo = wtAll + (size_t)14 * WSLOT; // 2
  short* wt_dec_cWv = wtAll + (size_t)16 * WSLOT; // 2
  short* wt_dec_cWo = wtAll + (size_t)18 * WSLOT; // 2
  short* wt_dec_c1 = wtAll + (size_t)20 * WSLOT;  // 2
  short* wt_dec_c2 = wtAll + (size_t)22 * WSLOT;  // 2

  // ----- phase 0 -----
  table_init_kernel<<<dim3(14), dim3(256), 0, stream>>>(tab, twg);
  prep_wt_multi_kernel<<<dim3(16, 16, 3), dim3(32, 8), 0, stream>>>(enc_Wv, wt_enc_Wv);
  prep_wt_multi_kernel<<<dim3(16, 16, 3), dim3(32, 8), 0, stream>>>(enc_Wo, wt_enc_Wo);
  prep_wt_multi_kernel<<<dim3(16, 16, 3), dim3(32, 8), 0, stream>>>(enc_c1, wt_enc_c1);
  prep_wt_multi_kernel<<<dim3(16, 16, 3), dim3(32, 8), 0, stream>>>(enc_c2, wt_enc_c2);
  prep_wt_multi_kernel<<<dim3(16, 16, 2), dim3(32, 8), 0, stream>>>(dec_sWv, wt_dec_sWv);
  prep_wt_multi_kernel<<<dim3(16, 16, 2), dim3(32, 8), 0, stream>>>(dec_sWo, wt_dec_sWo);
  prep_wt_multi_kernel<<<dim3(16, 16, 2), dim3(32, 8), 0, stream>>>(dec_cWv, wt_dec_cWv);
  prep_wt_multi_kernel<<<dim3(16, 16, 2), dim3(32, 8), 0, stream>>>(dec_cWo, wt_dec_cWo);
  prep_wt_multi_kernel<<<dim3(16, 16, 2), dim3(32, 8), 0, stream>>>(dec_c1, wt_dec_c1);
  prep_wt_multi_kernel<<<dim3(16, 16, 2), dim3(32, 8), 0, stream>>>(dec_c2, wt_dec_c2);
  decomp7_kernel<<<dim3(MROWS), dim3(64), 0, stream>>>(x_enc, seas7, trend7tmp);
  mean_enc_kernel<<<dim3(56), dim3(64), 0, stream>>>(x_enc, mean7);
  build_inits_kernel<<<dim3((BATCH * LSEQ * 7 + 255) / 256), dim3(256), 0, stream>>>(
      seas7, trend7tmp, mean7, seasonal_init, trend_acc);
  embed_kernel<<<dim3(MROWS), dim3(256), 0, stream>>>(x_enc, emb_enc_W, mark_enc, tab, enc_out);
  embed_kernel<<<dim3(MROWS), dim3(256), 0, stream>>>(seasonal_init, emb_dec_W, mark_dec, tab, dec_out);

  // ----- encoder -----
  for (int l = 0; l < 3; ++l) {
    size_t wOff = (size_t)l * WSLOT, bOff = (size_t)l * DMODEL;
    run_attn(enc_out, enc_out, enc_out,
             enc_Wq + wOff, enc_bq + bOff, enc_Wk + wOff, enc_bk + bOff,
             wt_enc_Wv + wOff, enc_bv + bOff, wt_enc_Wo + wOff, enc_bo + bOff,
             b1, b2, b3, sc, stream);                                   // b3 = attn out
    add_kernel<<<dim3(2048), dim3(256), 0, stream>>>(enc_out, b3, b1, n4);
    launch_decomp512(b1, b2, nullptr, 0, stream);                       // x = b2
    launch_gemm_bf16(b2, wt_enc_c1 + wOff, nullptr, b3, stream);
    gelu_kernel<<<dim3(2048), dim3(256), 0, stream>>>(b3, n4);
    launch_gemm_bf16(b3, wt_enc_c2 + wOff, nullptr, b1, stream);
    add_kernel<<<dim3(2048), dim3(256), 0, stream>>>(b2, b1, b3, n4);
    launch_decomp512(b3, enc_out, nullptr, 0, stream);
  }
  layernorm_kernel<<<dim3(MROWS), dim3(256), 0, stream>>>(enc_out, enc_nw, enc_nb, b1);
  colsum_kernel<<<dim3(BATCH, 16), dim3(256), 0, stream>>>(b1, colpart);
  colmean_finish_kernel<<<dim3(16), dim3(256), 0, stream>>>(colpart, colmu);
  sub_colmean_kernel<<<dim3(MROWS), dim3(256), 0, stream>>>(b1, colmu, enc_out);

  // ----- decoder -----
  for (int l = 0; l < 2; ++l) {
    size_t wOff = (size_t)l * WSLOT, bOff = (size_t)l * DMODEL;
    run_attn(dec_out, dec_out, dec_out,
             dec_sWq + wOff, dec_sbq + bOff, dec_sWk + wOff, dec_sbk + bOff,
             wt_dec_sWv + wOff, dec_sbv + bOff, wt_dec_sWo + wOff, dec_sbo + bOff,
             b1, b2, b3, sc, stream);                                   // b3 = self-attn out
    add_kernel<<<dim3(2048), dim3(256), 0, stream>>>(dec_out, b3, b1, n4);
    launch_decomp512(b1, b2, tsum, 1, stream);                          // x=b2, tsum=t1
    // dec_out is dead until the end of the loop body — reuse it as a temp.
    run_attn(b2, enc_out, enc_out,
             dec_cWq + wOff, dec_cbq + bOff, dec_cWk + wOff, dec_cbk + bOff,
             wt_dec_cWv + wOff, dec_cbv + bOff, wt_dec_cWo + wOff, dec_cbo + bOff,
             b1, b3, dec_out, sc, stream);                              // dec_out = cross-attn out
    add_kernel<<<dim3(2048), dim3(256), 0, stream>>>(b2, dec_out, b1, n4);
    launch_decomp512(b1, b3, tsum, 2, stream);                          // x=b3, tsum+=t2
    launch_gemm_bf16(b3, wt_dec_c1 + wOff, nullptr, b1, stream);
    gelu_kernel<<<dim3(2048), dim3(256), 0, stream>>>(b1, n4);
    launch_gemm_bf16(b1, wt_dec_c2 + wOff, nullptr, b2, stream);
    add_kernel<<<dim3(2048), dim3(256), 0, stream>>>(b3, b2, b1, n4);
    launch_decomp512(b1, dec_out, tsum, 2, stream);
    trend_conv_kernel<<<dim3(MROWS), dim3(64), 0, stream>>>(
        tsum, dec_trendW + (size_t)l * 3 * DMODEL * 7, trend_acc);
  }
  layernorm_kernel<<<dim3(MROWS), dim3(256), 0, stream>>>(dec_out, dec_nw, dec_nb, b1);
  colsum_kernel<<<dim3(BATCH, 16), dim3(256), 0, stream>>>(b1, colpart);
  colmean_finish_kernel<<<dim3(16), dim3(256), 0, stream>>>(colpart, colmu);
  sub_colmean_kernel<<<dim3(MROWS), dim3(256), 0, stream>>>(b1, colmu, b2);
  final_proj_kernel<<<dim3(BATCH * 1024), dim3(64), 0, stream>>>(
      b2, proj_W, proj_b, trend_acc, (float*)d_out);
}

// Round 13
// 4993.891 us; speedup vs baseline: 1.0264x; 1.0264x over previous
//
#include <hip/hip_runtime.h>
#include <math.h>

#define BATCH 8
#define LSEQ 2048
#define DMODEL 512
#define TOPK 38
#define MROWS (BATCH * LSEQ) /* 16384 */
#define WSLOT (DMODEL * DMODEL) /* elements per weight slot */

typedef __attribute__((ext_vector_type(8))) short bf16x8;
typedef __attribute__((ext_vector_type(4))) float f32x4;

// ---------------------------------------------------------------------------
// utility
// ---------------------------------------------------------------------------
__device__ __forceinline__ float wave_sum(float v) {
#pragma unroll
  for (int off = 32; off > 0; off >>= 1) v += __shfl_down(v, off);
  return v;
}

__device__ __forceinline__ short f2bf(float f) {  // fp32 -> bf16 bits, RNE
  unsigned u = __float_as_uint(f);
  unsigned r = (u + 0x7fffu + ((u >> 16) & 1u)) >> 16;
  return (short)r;
}

// ---------------------------------------------------------------------------
// tables: temporal-embed rows 0..6 and FFT twiddles e^{-2pi i m/2048}, m<1024
// ---------------------------------------------------------------------------
__global__ void table_init_kernel(float* __restrict__ tab, float2* __restrict__ twg) {
  int i = blockIdx.x * 256 + threadIdx.x;
  if (i < 7 * DMODEL) {
    int p = i >> 9;
    int d = i & (DMODEL - 1);
    float div = expf((float)(d >> 1) * (-2.0f * 9.210340371976184f / 512.0f)); // ln(10000)
    float ang = (float)p * div;
    tab[i] = (d & 1) ? cosf(ang) : sinf(ang);
  }
  if (i < 1024) {
    float ang = -6.283185307179586f * (float)i / 2048.0f;
    float sn, cs;
    sincosf(ang, &sn, &cs);
    twg[i] = make_float2(cs, sn);
  }
}

// ---------------------------------------------------------------------------
// embedding: out[b,t,d] = circ_conv3(x(7ch)) + sum of 4 temporal table rows
// ---------------------------------------------------------------------------
__global__ __launch_bounds__(256) void embed_kernel(
    const float* __restrict__ x,    // (B,L,7)
    const float* __restrict__ W,    // (3,7,512)
    const int* __restrict__ mark,   // (B,L,4)
    const float* __restrict__ tab,  // (7,512)
    float* __restrict__ out)        // (B,L,512)
{
  __shared__ float xs[21];
  int bt = blockIdx.x;
  int b = bt >> 11, t = bt & (LSEQ - 1);
  int tid = threadIdx.x;
  if (tid < 21) {
    int j = tid / 7, c = tid - j * 7;
    int row = (t - 1 + j + LSEQ) & (LSEQ - 1);
    xs[tid] = x[((size_t)b * LSEQ + row) * 7 + c];
  }
  __syncthreads();
  const int* mk = mark + ((size_t)b * LSEQ + t) * 4;
  int m0 = mk[0], m1 = mk[1], m2 = mk[2], m3 = mk[3];
#pragma unroll
  for (int h = 0; h < 2; ++h) {
    int d = tid + h * 256;
    float acc = tab[m0 * DMODEL + d] + tab[m1 * DMODEL + d] +
                tab[m2 * DMODEL + d] + tab[m3 * DMODEL + d];
#pragma unroll
    for (int j = 0; j < 3; ++j)
#pragma unroll
      for (int c = 0; c < 7; ++c)
        acc += xs[j * 7 + c] * W[(size_t)((j * 7 + c) * DMODEL) + d];
    out[((size_t)b * LSEQ + t) * DMODEL + d] = acc;
  }
}

// ---------------------------------------------------------------------------
// series_decomp D=7 (phase 0 only): seasonal = x - movavg25, trend write
// ---------------------------------------------------------------------------
__global__ void decomp7_kernel(const float* __restrict__ x, float* __restrict__ seas,
                               float* __restrict__ trend)
{
  int bt = blockIdx.x;
  int b = bt >> 11, t = bt & (LSEQ - 1);
  const float* xb = x + (size_t)b * LSEQ * 7;
  for (int d = threadIdx.x; d < 7; d += blockDim.x) {
    float s = 0.f;
#pragma unroll
    for (int o = -12; o <= 12; ++o) {
      int tt = t + o;
      tt = tt < 0 ? 0 : (tt > LSEQ - 1 ? LSEQ - 1 : tt);
      s += xb[(size_t)tt * 7 + d];
    }
    float mov = s / 25.0f;
    size_t idx = ((size_t)b * LSEQ + t) * 7 + d;
    seas[idx] = x[idx] - mov;
    trend[idx] = mov;
  }
}

// ---------------------------------------------------------------------------
// fused (a+b) + series_decomp D=512. x = a[i]+b[i] (or just a if b null),
// staged in LDS; identical 25-term ascending sum => bit-identical to
// add_kernel followed by decomp.
// ---------------------------------------------------------------------------
__global__ __launch_bounds__(256) void add_decomp512_kernel(
    const float* __restrict__ a, const float* __restrict__ bsrc,
    float* __restrict__ seas, float* __restrict__ trend, int mode)
{
  __shared__ float ls[56][256];
  int tc = blockIdx.x;   // t-chunk of 32: 0..63
  int b = blockIdx.y;    // 0..7
  int dh = blockIdx.z;   // d-half: 0..1
  int tid = threadIdx.x;
  int d = dh * 256 + tid;
  const float* ab = a + (size_t)b * LSEQ * DMODEL;
  const float* bb = bsrc ? bsrc + (size_t)b * LSEQ * DMODEL : nullptr;
  int t0 = tc * 32;
#pragma unroll 1
  for (int r = 0; r < 56; ++r) {
    int tg = t0 - 12 + r;
    tg = tg < 0 ? 0 : (tg > LSEQ - 1 ? LSEQ - 1 : tg);
    size_t o = (size_t)tg * DMODEL + d;
    float v = ab[o];
    if (bb) v += bb[o];
    ls[r][tid] = v;
  }
  __syncthreads();
#pragma unroll 1
  for (int tl = 0; tl < 32; ++tl) {
    float s = 0.f;
#pragma unroll
    for (int o = -12; o <= 12; ++o) s += ls[tl + 12 + o][tid];
    float mov = s / 25.0f;
    size_t idx = ((size_t)b * LSEQ + t0 + tl) * DMODEL + d;
    seas[idx] = ls[tl + 12][tid] - mov;
    if (mode == 1) trend[idx] = mov;
    else if (mode == 2) trend[idx] += mov;
  }
}

// ---------------------------------------------------------------------------
// fp32 SGEMM (Q/K projections — precision-critical top-k path).
// 64x128 tile, BK=16. n-fragments remapped to tx*4 / 64+tx*4 so LDS B-reads
// hit banks at stride 4 (2-way aliasing = free) instead of stride 8 (4-way).
// Per-output k-ascending fmaf chain identical => bit-identical results.
// ---------------------------------------------------------------------------
__global__ __launch_bounds__(256) void sgemm_kernel(
    const float* __restrict__ A, const float* __restrict__ B,
    const float* __restrict__ bias, float* __restrict__ C,
    int M, int N, int K)
{
  __shared__ float As[16][68];   // [k][m]
  __shared__ float Bs[16][132];  // [k][n]
  int m0 = blockIdx.x * 64;
  int n0 = blockIdx.y * 128;
  int tid = threadIdx.x;
  int tx = tid & 15, ty = tid >> 4;  // tx: n-frag base, ty: m-frag base
  float acc[4][8];
#pragma unroll
  for (int i = 0; i < 4; ++i)
#pragma unroll
    for (int j = 0; j < 8; ++j) acc[i][j] = 0.f;

  int ar = tid >> 2;        // 0..63 (m)
  int ac = (tid & 3) << 2;  // 0,4,8,12 (k)
  int br = tid >> 5;        // 0..7 (k)
  int bc = (tid & 31) << 2; // 0..124 (n)

  for (int k0 = 0; k0 < K; k0 += 16) {
    float4 a0 = *(const float4*)(A + (size_t)(m0 + ar) * K + k0 + ac);
    float4 b0 = *(const float4*)(B + (size_t)(k0 + br) * N + n0 + bc);
    float4 b1 = *(const float4*)(B + (size_t)(k0 + 8 + br) * N + n0 + bc);
    As[ac + 0][ar] = a0.x; As[ac + 1][ar] = a0.y; As[ac + 2][ar] = a0.z; As[ac + 3][ar] = a0.w;
    *(float4*)&Bs[br][bc] = b0;
    *(float4*)&Bs[br + 8][bc] = b1;
    __syncthreads();
#pragma unroll
    for (int k = 0; k < 16; ++k) {
      float av[4], bv[8];
      *(float4*)(av)     = *(const float4*)&As[k][ty * 4];
      *(float4*)(bv)     = *(const float4*)&Bs[k][tx * 4];
      *(float4*)(bv + 4) = *(const float4*)&Bs[k][64 + tx * 4];
#pragma unroll
      for (int i = 0; i < 4; ++i)
#pragma unroll
        for (int j = 0; j < 8; ++j)
          acc[i][j] = fmaf(av[i], bv[j], acc[i][j]);
    }
    __syncthreads();
  }
#pragma unroll
  for (int i = 0; i < 4; ++i) {
    int m = m0 + ty * 4 + i;
#pragma unroll
    for (int h = 0; h < 2; ++h) {
      int n = n0 + h * 64 + tx * 4;
      float* cr = C + (size_t)m * N + n;
      float4 v = make_float4(acc[i][h * 4], acc[i][h * 4 + 1],
                             acc[i][h * 4 + 2], acc[i][h * 4 + 3]);
      if (bias) {
        const float* bp = bias + n;
        v.x += bp[0]; v.y += bp[1]; v.z += bp[2]; v.w += bp[3];
      }
      *(float4*)cr = v;
    }
  }
}

// ---------------------------------------------------------------------------
// weight prep (batched): W fp32 (nl,512,512) -> Wt bf16 (nl,512t,512)
// ---------------------------------------------------------------------------
__global__ void prep_wt_multi_kernel(const float* __restrict__ W, short* __restrict__ Wt) {
  __shared__ float tile[32][33];
  int layer = blockIdx.z;
  const float* src = W + (size_t)layer * WSLOT;
  short* dst = Wt + (size_t)layer * WSLOT;
  int k0 = blockIdx.x << 5, n0 = blockIdx.y << 5;
  for (int i = threadIdx.y; i < 32; i += 8)
    tile[i][threadIdx.x] = src[(size_t)(k0 + i) * DMODEL + n0 + threadIdx.x];
  __syncthreads();
  for (int i = threadIdx.y; i < 32; i += 8)
    dst[(size_t)(n0 + i) * DMODEL + k0 + threadIdx.x] = f2bf(tile[threadIdx.x][i]);
}

// ---------------------------------------------------------------------------
// bf16 MFMA GEMM (V/O/FFN): C = A @ W (+bias, optional gelu), Wt[n][k] bf16.
// 128x128, BK=32. gelu applied in epilogue on the identical fp32 value =>
// bit-identical to separate gelu kernel.
// ---------------------------------------------------------------------------
__global__ __launch_bounds__(256) void gemm_bf16_kernel(
    const float* __restrict__ A, const short* __restrict__ Wt,
    const float* __restrict__ bias, float* __restrict__ C, int applyGelu)
{
  const int K = DMODEL, N = DMODEL;
  __shared__ short As[128][40];  // [m][k] bf16
  __shared__ short Bs[128][40];  // [n][k] bf16
  int m0 = blockIdx.x * 128;
  int n0 = blockIdx.y * 128;
  int tid = threadIdx.x;
  int lane = tid & 63;
  int wave = tid >> 6;
  int wm = (wave >> 1) * 64;
  int wn = (wave & 1) * 64;
  int lr = lane & 15;
  int lk = (lane >> 4) * 8;

  f32x4 acc[4][4];
#pragma unroll
  for (int i = 0; i < 4; ++i)
#pragma unroll
    for (int j = 0; j < 4; ++j) acc[i][j] = (f32x4){0.f, 0.f, 0.f, 0.f};

  for (int k0 = 0; k0 < K; k0 += 32) {
#pragma unroll
    for (int i = 0; i < 4; ++i) {
      int f = tid + i * 256;
      int row = f >> 3, c4 = (f & 7) << 2;
      float4 v = *(const float4*)(A + (size_t)(m0 + row) * K + k0 + c4);
      short4 s = make_short4(f2bf(v.x), f2bf(v.y), f2bf(v.z), f2bf(v.w));
      *(short4*)&As[row][c4] = s;
    }
#pragma unroll
    for (int i = 0; i < 2; ++i) {
      int f = tid + i * 256;
      int row = f >> 2, c8 = (f & 3) << 3;
      *(int4*)&Bs[row][c8] = *(const int4*)(Wt + (size_t)(n0 + row) * K + k0 + c8);
    }
    __syncthreads();
    bf16x8 af[4], bfr[4];
#pragma unroll
    for (int m = 0; m < 4; ++m) af[m] = *(const bf16x8*)&As[wm + m * 16 + lr][lk];
#pragma unroll
    for (int n = 0; n < 4; ++n) bfr[n] = *(const bf16x8*)&Bs[wn + n * 16 + lr][lk];
#pragma unroll
    for (int m = 0; m < 4; ++m)
#pragma unroll
      for (int n = 0; n < 4; ++n)
        acc[m][n] = __builtin_amdgcn_mfma_f32_16x16x32_bf16(af[m], bfr[n], acc[m][n], 0, 0, 0);
    __syncthreads();
  }
  const float gk = 0.7071067811865475f;
  int orow = m0 + wm + (lane >> 4) * 4;
  int ocol = n0 + wn + lr;
#pragma unroll
  for (int m = 0; m < 4; ++m)
#pragma unroll
    for (int n = 0; n < 4; ++n) {
      int col = ocol + n * 16;
      float bv = bias ? bias[col] : 0.f;
#pragma unroll
      for (int r = 0; r < 4; ++r) {
        float v = acc[m][n][r] + bv;
        if (applyGelu) v = 0.5f * v * (1.f + erff(v * gk));
        C[(size_t)(orow + m * 16 + r) * N + col] = v;
      }
    }
}

// ---------------------------------------------------------------------------
// transpose (B,2048,512) -> (B,512,2048)
// ---------------------------------------------------------------------------
__global__ void transpose_kernel(const float* __restrict__ in, float* __restrict__ out) {
  __shared__ float tile[32][33];
  int b = blockIdx.x;
  int r0 = blockIdx.y << 5;
  int c0 = blockIdx.z << 5;
  const float* ib = in + (size_t)b * LSEQ * DMODEL;
  float* ob = out + (size_t)b * LSEQ * DMODEL;
  for (int i = threadIdx.y; i < 32; i += 8)
    tile[i][threadIdx.x] = ib[(size_t)(r0 + i) * DMODEL + c0 + threadIdx.x];
  __syncthreads();
  for (int i = threadIdx.y; i < 32; i += 8)
    ob[(size_t)(c0 + i) * LSEQ + r0 + threadIdx.x] = tile[threadIdx.x][i];
}

// ---------------------------------------------------------------------------
// in-place radix-2 DIT FFT, 2048 pts, input pre-bit-reversed, 256 threads
// ---------------------------------------------------------------------------
__device__ __forceinline__ void fft2048_lds(float2* buf, const float2* tw, int tid, int inverse) {
#pragma unroll 1
  for (int s = 1; s <= 11; ++s) {
    int half = 1 << (s - 1);
#pragma unroll 1
    for (int bf = tid; bf < 1024; bf += 256) {
      int j = bf & (half - 1);
      int i0 = ((bf >> (s - 1)) << s) | j;
      int i1 = i0 + half;
      float2 w = tw[j << (11 - s)];
      float wy = inverse ? -w.y : w.y;
      float2 a = buf[i0], b = buf[i1];
      float tr = b.x * w.x - b.y * wy;
      float ti = b.x * wy + b.y * w.x;
      buf[i0] = make_float2(a.x + tr, a.y + ti);
      buf[i1] = make_float2(a.x - tr, a.y - ti);
    }
    __syncthreads();
  }
}

// ---------------------------------------------------------------------------
// packed q+ik FFT per channel, accumulate product spectrum over 8 channels
// per block; 64 blocks per batch -> partial[b*64+g][f]
// ---------------------------------------------------------------------------
__global__ __launch_bounds__(256) void corr_spectrum_kernel(
    const float* __restrict__ qt, const float* __restrict__ kt,  // (B,512,2048)
    const float2* __restrict__ twg, float2* __restrict__ partial)
{
  __shared__ float2 buf[2048];
  __shared__ float2 acc[2048];
  __shared__ float2 twl[1024];
  int tid = threadIdx.x;
  int b = blockIdx.x >> 6;
  int g = blockIdx.x & 63;
  for (int i = tid; i < 1024; i += 256) twl[i] = twg[i];
  for (int i = tid; i < 2048; i += 256) acc[i] = make_float2(0.f, 0.f);
  __syncthreads();
#pragma unroll 1
  for (int ch = 0; ch < 8; ++ch) {
    int d = (g << 3) + ch;
    const float* qr = qt + ((size_t)b * DMODEL + d) * LSEQ;
    const float* kr = kt + ((size_t)b * DMODEL + d) * LSEQ;
    for (int i = tid; i < 2048; i += 256) {
      int rev = __brev((unsigned)i) >> 21;
      buf[rev] = make_float2(qr[i], kr[i]);
    }
    __syncthreads();
    fft2048_lds(buf, twl, tid, 0);
    for (int i = tid; i < 2048; i += 256) {
      float2 z1 = buf[i];
      float2 z2 = buf[(2048 - i) & 2047];
      float Qr = 0.5f * (z1.x + z2.x);
      float Qi = 0.5f * (z1.y - z2.y);
      float Kr = 0.5f * (z1.y + z2.y);
      float Ki = -0.5f * (z1.x - z2.x);
      acc[i].x += Qr * Kr + Qi * Ki;   // Q * conj(K)
      acc[i].y += Qi * Kr - Qr * Ki;
    }
    __syncthreads();
  }
  float2* op = partial + (size_t)blockIdx.x * 2048;
  for (int i = tid; i < 2048; i += 256) op[i] = acc[i];
}

// many-block reduction of the 64 partial spectra per batch -> spec[b][2048]
__global__ __launch_bounds__(256) void reduce_partials_kernel(
    const float2* __restrict__ partial, float2* __restrict__ spec)
{
  int b = blockIdx.x;
  int i = blockIdx.y * 256 + threadIdx.x;
  const float2* pp = partial + ((size_t)b * 64) * 2048 + i;
  float sx = 0.f, sy = 0.f;
#pragma unroll 8
  for (int g = 0; g < 64; ++g) {
    float2 v = pp[(size_t)g * 2048];
    sx += v.x; sy += v.y;
  }
  spec[(size_t)b * 2048 + i] = make_float2(sx, sy);
}

// inverse FFT of summed spectrum -> mean_value (B,2048)
__global__ __launch_bounds__(256) void ifft_kernel(
    const float2* __restrict__ spec, const float2* __restrict__ twg,
    float* __restrict__ mv)
{
  __shared__ float2 buf[2048];
  __shared__ float2 twl[1024];
  int tid = threadIdx.x;
  int b = blockIdx.x;
  for (int i = tid; i < 1024; i += 256) twl[i] = twg[i];
  for (int i = tid; i < 2048; i += 256) {
    int rev = __brev((unsigned)i) >> 21;
    buf[rev] = spec[(size_t)b * 2048 + i];
  }
  __syncthreads();
  fft2048_lds(buf, twl, tid, 1);
  const float scale = 1.0f / (2048.0f * 512.0f);  // 1/L (irfft) * 1/(H*E) (mean)
  for (int i = tid; i < 2048; i += 256) mv[(size_t)b * 2048 + i] = buf[i].x * scale;
}

// top-38 of batch-summed mean_value, then per-batch softmax weights
__global__ void topk_kernel(const float* __restrict__ mv, int* __restrict__ idxOut,
                            float* __restrict__ wOut)
{
  __shared__ float cm[2048];
  __shared__ float rmax[256];
  __shared__ int rIdx[256];
  __shared__ int sIdx[TOPK];
  int tid = threadIdx.x;
  for (int i = tid; i < 2048; i += 256) {
    float s = 0.f;
#pragma unroll
    for (int b = 0; b < BATCH; ++b) s += mv[(size_t)b * 2048 + i];
    cm[i] = s;
  }
  __syncthreads();
  for (int it = 0; it < TOPK; ++it) {
    float best = -1e30f; int bi = 0;
    for (int i = tid; i < 2048; i += 256)
      if (cm[i] > best) { best = cm[i]; bi = i; }
    rmax[tid] = best; rIdx[tid] = bi;
    __syncthreads();
    for (int s = 128; s > 0; s >>= 1) {
      if (tid < s && rmax[tid + s] > rmax[tid]) { rmax[tid] = rmax[tid + s]; rIdx[tid] = rIdx[tid + s]; }
      __syncthreads();
    }
    if (tid == 0) { sIdx[it] = rIdx[0]; idxOut[it] = rIdx[0]; cm[rIdx[0]] = -1e30f; }
    __syncthreads();
  }
  if (tid < BATCH) {
    int b = tid;
    float vals[TOPK];
    float m = -1e30f;
    for (int j = 0; j < TOPK; ++j) { vals[j] = mv[(size_t)b * 2048 + sIdx[j]]; m = fmaxf(m, vals[j]); }
    float s = 0.f;
    for (int j = 0; j < TOPK; ++j) { vals[j] = expf(vals[j] - m); s += vals[j]; }
    for (int j = 0; j < TOPK; ++j) wOut[b * TOPK + j] = vals[j] / s;
  }
}

// out[b,t,d] = sum_j w[b,j] * v[b,(t+idx_j)%L,d]
__global__ __launch_bounds__(256) void shift_sum_kernel(
    const float* __restrict__ v, const int* __restrict__ idx,
    const float* __restrict__ w, float* __restrict__ out)
{
  __shared__ int sidx[TOPK];
  __shared__ float sw[TOPK];
  int bt = blockIdx.x;
  int b = bt & 7, t = bt >> 3;
  int tid = threadIdx.x;
  if (tid < TOPK) { sidx[tid] = idx[tid]; sw[tid] = w[b * TOPK + tid]; }
  __syncthreads();
  float a0 = 0.f, a1 = 0.f;
  const float* vb = v + (size_t)b * LSEQ * DMODEL;
#pragma unroll 1
  for (int j = 0; j < TOPK; ++j) {
    int row = (t + sidx[j]) & (LSEQ - 1);
    const float* vr = vb + (size_t)row * DMODEL;
    a0 = fmaf(sw[j], vr[tid], a0);
    a1 = fmaf(sw[j], vr[tid + 256], a1);
  }
  size_t o = ((size_t)b * LSEQ + t) * DMODEL;
  out[o + tid] = a0;
  out[o + tid + 256] = a1;
}

// row layernorm over 512 (eps 1e-5)
__global__ __launch_bounds__(256) void layernorm_kernel(
    const float* __restrict__ x, const float* __restrict__ w,
    const float* __restrict__ bb, float* __restrict__ out)
{
  __shared__ float red[256];
  int row = blockIdx.x;
  int tid = threadIdx.x;
  const float* xr = x + (size_t)row * DMODEL;
  float v0 = xr[tid], v1 = xr[tid + 256];
  red[tid] = v0 + v1;
  __syncthreads();
  for (int o = 128; o > 0; o >>= 1) {
    if (tid < o) red[tid] += red[tid + o];
    __syncthreads();
  }
  float mu = red[0] / 512.0f;
  __syncthreads();
  float d0 = v0 - mu, d1 = v1 - mu;
  red[tid] = d0 * d0 + d1 * d1;
  __syncthreads();
  for (int o = 128; o > 0; o >>= 1) {
    if (tid < o) red[tid] += red[tid + o];
    __syncthreads();
  }
  float var = red[0] / 512.0f;
  float inv = 1.0f / sqrtf(var + 1e-5f);
  out[(size_t)row * DMODEL + tid] = d0 * inv * w[tid] + bb[tid];
  out[(size_t)row * DMODEL + tid + 256] = d1 * inv * w[tid + 256] + bb[tid + 256];
}

// column (time-axis) mean subtraction: 3 stages
__global__ __launch_bounds__(256) void colsum_kernel(const float* __restrict__ x,
                                                     float* __restrict__ part)
{
  int b = blockIdx.x, ch = blockIdx.y;
  const float* xb = x + ((size_t)b * LSEQ + (size_t)ch * 128) * DMODEL;
  float s0 = 0.f, s1 = 0.f;
#pragma unroll 1
  for (int t = 0; t < 128; ++t) {
    s0 += xb[(size_t)t * DMODEL + threadIdx.x];
    s1 += xb[(size_t)t * DMODEL + threadIdx.x + 256];
  }
  part[(size_t)(b * 16 + ch) * DMODEL + threadIdx.x] = s0;
  part[(size_t)(b * 16 + ch) * DMODEL + threadIdx.x + 256] = s1;
}

__global__ void colmean_finish_kernel(const float* __restrict__ part, float* __restrict__ mu) {
  int i = blockIdx.x * 256 + threadIdx.x;
  if (i < BATCH * DMODEL) {
    int b = i / DMODEL, d = i - b * DMODEL;
    float s = 0.f;
#pragma unroll
    for (int c = 0; c < 16; ++c) s += part[(size_t)(b * 16 + c) * DMODEL + d];
    mu[i] = s / (float)LSEQ;
  }
}

__global__ __launch_bounds__(256) void sub_colmean_kernel(
    const float* __restrict__ x, const float* __restrict__ mu, float* __restrict__ out)
{
  int bt = blockIdx.x;
  int b = bt >> 11;
  size_t base = (size_t)bt * DMODEL;
  int d0 = threadIdx.x, d1 = threadIdx.x + 256;
  out[base + d0] = x[base + d0] - mu[b * DMODEL + d0];
  out[base + d1] = x[base + d1] - mu[b * DMODEL + d1];
}

// ---------------------------------------------------------------------------
// small kernels
// ---------------------------------------------------------------------------
__global__ void mean_enc_kernel(const float* __restrict__ x, float* __restrict__ mean7) {
  int b = blockIdx.x / 7, c = blockIdx.x % 7;
  float s = 0.f;
  for (int t = threadIdx.x; t < LSEQ; t += 64) s += x[((size_t)b * LSEQ + t) * 7 + c];
  s = wave_sum(s);
  if (threadIdx.x == 0) mean7[b * 7 + c] = s / 2048.0f;
}

__global__ void build_inits_kernel(const float* __restrict__ seas7, const float* __restrict__ trend7,
                                   const float* __restrict__ mean7,
                                   float* __restrict__ seasonal_init, float* __restrict__ trend_acc)
{
  int i = blockIdx.x * 256 + threadIdx.x;
  if (i >= BATCH * LSEQ * 7) return;
  int c = i % 7;
  int bt = i / 7;
  int t = bt & (LSEQ - 1);
  int b = bt >> 11;
  if (t < 1024) {
    size_t src = ((size_t)b * LSEQ + (t + 1024)) * 7 + c;
    seasonal_init[i] = seas7[src];
    trend_acc[i] = trend7[src];
  } else {
    seasonal_init[i] = 0.f;
    trend_acc[i] = mean7[b * 7 + c];
  }
}

// trend += circ_conv3(x(512ch), W(3,512,7)); one wave per (b,t)
__global__ void trend_conv_kernel(const float* __restrict__ x, const float* __restrict__ W,
                                  float* __restrict__ trend)
{
  int bt = blockIdx.x;
  int b = bt >> 11, t = bt & (LSEQ - 1);
  int lane = threadIdx.x;
  float acc[7] = {0, 0, 0, 0, 0, 0, 0};
#pragma unroll
  for (int j = 0; j < 3; ++j) {
    int row = (t - 1 + j + LSEQ) & (LSEQ - 1);
    const float* xr = x + ((size_t)b * LSEQ + row) * DMODEL;
    const float* wj = W + (size_t)j * DMODEL * 7;
    for (int d = lane; d < DMODEL; d += 64) {
      float xv = xr[d];
      const float* wr = wj + d * 7;
#pragma unroll
      for (int c = 0; c < 7; ++c) acc[c] += xv * wr[c];
    }
  }
#pragma unroll
  for (int c = 0; c < 7; ++c) {
    float s = wave_sum(acc[c]);
    if (lane == 0) trend[((size_t)b * LSEQ + t) * 7 + c] += s;
  }
}

// final: d_out[b,tt,c] = trend[b,1024+tt,c] + x[b,1024+tt,:] @ projW + projb
__global__ void final_proj_kernel(const float* __restrict__ x, const float* __restrict__ W,
                                  const float* __restrict__ bias, const float* __restrict__ trend,
                                  float* __restrict__ out)
{
  int bt = blockIdx.x;
  int b = bt >> 10, tt = bt & 1023;
  int t = tt + 1024;
  int lane = threadIdx.x;
  const float* xr = x + ((size_t)b * LSEQ + t) * DMODEL;
  float acc[7] = {0, 0, 0, 0, 0, 0, 0};
  for (int d = lane; d < DMODEL; d += 64) {
    float xv = xr[d];
    const float* wr = W + d * 7;
#pragma unroll
    for (int c = 0; c < 7; ++c) acc[c] += xv * wr[c];
  }
#pragma unroll
  for (int c = 0; c < 7; ++c) {
    float s = wave_sum(acc[c]);
    if (lane == 0)
      out[((size_t)b * 1024 + tt) * 7 + c] = s + bias[c] + trend[((size_t)b * LSEQ + t) * 7 + c];
  }
}

// ---------------------------------------------------------------------------
// host orchestration
// ---------------------------------------------------------------------------
static inline void launch_sgemm(const float* A, const float* W, const float* bias, float* C,
                                hipStream_t s)
{
  sgemm_kernel<<<dim3(MROWS / 64, DMODEL / 128), dim3(256), 0, s>>>(
      A, W, bias, C, MROWS, DMODEL, DMODEL);
}

static inline void launch_gemm_bf16(const float* A, const short* Wt, const float* bias, float* C,
                                    int gelu, hipStream_t s)
{
  gemm_bf16_kernel<<<dim3(MROWS / 128, DMODEL / 128), dim3(256), 0, s>>>(A, Wt, bias, C, gelu);
}

static inline void launch_add_decomp(const float* a, const float* b, float* seas, float* trend,
                                     int mode, hipStream_t s)
{
  add_decomp512_kernel<<<dim3(64, BATCH, 2), dim3(256), 0, s>>>(a, b, seas, trend, mode);
}

struct AttnScratch {
  float2* partial;
  float2* spec;
  float* mv;
  int* idx;
  float* w;
  const float2* twg;
};

// Q/K: fp32 SGEMM (precision-critical top-k path). V/O: bf16 MFMA.
static void run_attn(const float* qx, const float* kx, const float* vx,
                     const float* Wq, const float* bq, const float* Wk, const float* bk,
                     const short* wtV, const float* bv, const short* wtO, const float* bo,
                     float* t1, float* t2, float* t3, const AttnScratch& sc, hipStream_t s)
{
  dim3 tg(BATCH, LSEQ / 32, DMODEL / 32);
  launch_sgemm(qx, Wq, bq, t1, s);
  transpose_kernel<<<tg, dim3(32, 8), 0, s>>>(t1, t2);             // t2 = q^T
  launch_sgemm(kx, Wk, bk, t1, s);
  transpose_kernel<<<tg, dim3(32, 8), 0, s>>>(t1, t3);             // t3 = k^T
  launch_gemm_bf16(vx, wtV, bv, t1, 0, s);                         // t1 = v
  corr_spectrum_kernel<<<dim3(BATCH * 64), dim3(256), 0, s>>>(t2, t3, sc.twg, sc.partial);
  reduce_partials_kernel<<<dim3(BATCH, 8), dim3(256), 0, s>>>(sc.partial, sc.spec);
  ifft_kernel<<<dim3(BATCH), dim3(256), 0, s>>>(sc.spec, sc.twg, sc.mv);
  topk_kernel<<<dim3(1), dim3(256), 0, s>>>(sc.mv, sc.idx, sc.w);
  shift_sum_kernel<<<dim3(MROWS), dim3(256), 0, s>>>(t1, sc.idx, sc.w, t2);  // t2 = agg
  launch_gemm_bf16(t2, wtO, bo, t3, 0, s);                         // t3 = attn out
}

extern "C" void kernel_launch(void* const* d_in, const int* in_sizes, int n_in,
                              void* d_out, int out_size, void* d_ws, size_t ws_size,
                              hipStream_t stream)
{
  if (n_in < 41) return;  // defensive: unexpected harness input layout

  const float* x_enc    = (const float*)d_in[0];
  const int*   mark_enc = (const int*)d_in[1];
  const int*   mark_dec = (const int*)d_in[3];
  const float* emb_enc_W = (const float*)d_in[4];
  const float* emb_dec_W = (const float*)d_in[5];
  const float* enc_Wq = (const float*)d_in[6];
  const float* enc_bq = (const float*)d_in[7];
  const float* dec_sWq = (const float*)d_in[8];
  const float* dec_sbq = (const float*)d_in[9];
  const float* dec_cWq = (const float*)d_in[10];
  const float* dec_cbq = (const float*)d_in[11];
  const float* enc_Wk = (const float*)d_in[12];
  const float* enc_bk = (const float*)d_in[13];
  const float* dec_sWk = (const float*)d_in[14];
  const float* dec_sbk = (const float*)d_in[15];
  const float* dec_cWk = (const float*)d_in[16];
  const float* dec_cbk = (const float*)d_in[17];
  const float* enc_Wv = (const float*)d_in[18];
  const float* enc_bv = (const float*)d_in[19];
  const float* dec_sWv = (const float*)d_in[20];
  const float* dec_sbv = (const float*)d_in[21];
  const float* dec_cWv = (const float*)d_in[22];
  const float* dec_cbv = (const float*)d_in[23];
  const float* enc_Wo = (const float*)d_in[24];
  const float* enc_bo = (const float*)d_in[25];
  const float* dec_sWo = (const float*)d_in[26];
  const float* dec_sbo = (const float*)d_in[27];
  const float* dec_cWo = (const float*)d_in[28];
  const float* dec_cbo = (const float*)d_in[29];
  const float* enc_c1 = (const float*)d_in[30];
  const float* enc_c2 = (const float*)d_in[31];
  const float* enc_nw = (const float*)d_in[32];
  const float* enc_nb = (const float*)d_in[33];
  const float* dec_c1 = (const float*)d_in[34];
  const float* dec_c2 = (const float*)d_in[35];
  const float* dec_trendW = (const float*)d_in[36];
  const float* dec_nw = (const float*)d_in[37];
  const float* dec_nb = (const float*)d_in[38];
  const float* proj_W = (const float*)d_in[39];
  const float* proj_b = (const float*)d_in[40];

  (void)in_sizes; (void)out_size;

  // ----- workspace carve (~225 MB) -----
  const size_t BIG = (size_t)MROWS * DMODEL * sizeof(float);  // 33.55 MB
  char* p = (char*)d_ws;
  float* enc_out = (float*)p; p += BIG;
  float* dec_out = (float*)p; p += BIG;
  float* tsum    = (float*)p; p += BIG;
  float* b1 = (float*)p; p += BIG;
  float* b2 = (float*)p; p += BIG;
  float* b3 = (float*)p; p += BIG;
  float2* partial = (float2*)p; p += (size_t)BATCH * 64 * 2048 * sizeof(float2);
  float2* specbuf = (float2*)p; p += (size_t)BATCH * 2048 * sizeof(float2);
  short* wtAll = (short*)p; p += (size_t)24 * WSLOT * sizeof(short);  // 12.58 MB
  float* mv = (float*)p; p += (size_t)BATCH * 2048 * sizeof(float);
  float* tab = (float*)p; p += 7 * DMODEL * sizeof(float);
  float2* twg = (float2*)p; p += 1024 * sizeof(float2);
  float* seas7 = (float*)p; p += (size_t)BATCH * LSEQ * 7 * sizeof(float);
  float* trend7tmp = (float*)p; p += (size_t)BATCH * LSEQ * 7 * sizeof(float);
  float* seasonal_init = (float*)p; p += (size_t)BATCH * LSEQ * 7 * sizeof(float);
  float* trend_acc = (float*)p; p += (size_t)BATCH * LSEQ * 7 * sizeof(float);
  float* colpart = (float*)p; p += (size_t)BATCH * 16 * DMODEL * sizeof(float);
  float* colmu = (float*)p; p += (size_t)BATCH * DMODEL * sizeof(float);
  float* mean7 = (float*)p; p += 256;
  int* idxbuf = (int*)p; p += 256;
  float* wbuf = (float*)p; p += 2048;
  if ((size_t)(p - (char*)d_ws) > ws_size) return;  // insufficient scratch

  AttnScratch sc{partial, specbuf, mv, idxbuf, wbuf, twg};

  // bf16 weight slots (precomputed once): index in units of WSLOT
  short* wt_enc_Wv = wtAll + (size_t)0 * WSLOT;   // 3 layers
  short* wt_enc_Wo = wtAll + (size_t)3 * WSLOT;   // 3
  short* wt_enc_c1 = wtAll + (size_t)6 * WSLOT;   // 3
  short* wt_enc_c2 = wtAll + (size_t)9 * WSLOT;   // 3
  short* wt_dec_sWv = wtAll + (size_t)12 * WSLOT; // 2
  short* wt_dec_sWo = wtAll + (size_t)14 * WSLOT; // 2
  short* wt_dec_cWv = wtAll + (size_t)16 * WSLOT; // 2
  short* wt_dec_cWo = wtAll + (size_t)18 * WSLOT; // 2
  short* wt_dec_c1 = wtAll + (size_t)20 * WSLOT;  // 2
  short* wt_dec_c2 = wtAll + (size_t)22 * WSLOT;  // 2

  // ----- phase 0 -----
  table_init_kernel<<<dim3(14), dim3(256), 0, stream>>>(tab, twg);
  prep_wt_multi_kernel<<<dim3(16, 16, 3), dim3(32, 8), 0, stream>>>(enc_Wv, wt_enc_Wv);
  prep_wt_multi_kernel<<<dim3(16, 16, 3), dim3(32, 8), 0, stream>>>(enc_Wo, wt_enc_Wo);
  prep_wt_multi_kernel<<<dim3(16, 16, 3), dim3(32, 8), 0, stream>>>(enc_c1, wt_enc_c1);
  prep_wt_multi_kernel<<<dim3(16, 16, 3), dim3(32, 8), 0, stream>>>(enc_c2, wt_enc_c2);
  prep_wt_multi_kernel<<<dim3(16, 16, 2), dim3(32, 8), 0, stream>>>(dec_sWv, wt_dec_sWv);
  prep_wt_multi_kernel<<<dim3(16, 16, 2), dim3(32, 8), 0, stream>>>(dec_sWo, wt_dec_sWo);
  prep_wt_multi_kernel<<<dim3(16, 16, 2), dim3(32, 8), 0, stream>>>(dec_cWv, wt_dec_cWv);
  prep_wt_multi_kernel<<<dim3(16, 16, 2), dim3(32, 8), 0, stream>>>(dec_cWo, wt_dec_cWo);
  prep_wt_multi_kernel<<<dim3(16, 16, 2), dim3(32, 8), 0, stream>>>(dec_c1, wt_dec_c1);
  prep_wt_multi_kernel<<<dim3(16, 16, 2), dim3(32, 8), 0, stream>>>(dec_c2, wt_dec_c2);
  decomp7_kernel<<<dim3(MROWS), dim3(64), 0, stream>>>(x_enc, seas7, trend7tmp);
  mean_enc_kernel<<<dim3(56), dim3(64), 0, stream>>>(x_enc, mean7);
  build_inits_kernel<<<dim3((BATCH * LSEQ * 7 + 255) / 256), dim3(256), 0, stream>>>(
      seas7, trend7tmp, mean7, seasonal_init, trend_acc);
  embed_kernel<<<dim3(MROWS), dim3(256), 0, stream>>>(x_enc, emb_enc_W, mark_enc, tab, enc_out);
  embed_kernel<<<dim3(MROWS), dim3(256), 0, stream>>>(seasonal_init, emb_dec_W, mark_dec, tab, dec_out);

  // ----- encoder -----
  for (int l = 0; l < 3; ++l) {
    size_t wOff = (size_t)l * WSLOT, bOff = (size_t)l * DMODEL;
    run_attn(enc_out, enc_out, enc_out,
             enc_Wq + wOff, enc_bq + bOff, enc_Wk + wOff, enc_bk + bOff,
             wt_enc_Wv + wOff, enc_bv + bOff, wt_enc_Wo + wOff, enc_bo + bOff,
             b1, b2, b3, sc, stream);                                   // b3 = attn out
    launch_add_decomp(enc_out, b3, b2, nullptr, 0, stream);             // x = b2
    launch_gemm_bf16(b2, wt_enc_c1 + wOff, nullptr, b3, 1, stream);     // b3 = gelu(x@c1)
    launch_gemm_bf16(b3, wt_enc_c2 + wOff, nullptr, b1, 0, stream);     // b1 = y
    launch_add_decomp(b2, b1, enc_out, nullptr, 0, stream);             // enc_out = seas(x+y)
  }
  layernorm_kernel<<<dim3(MROWS), dim3(256), 0, stream>>>(enc_out, enc_nw, enc_nb, b1);
  colsum_kernel<<<dim3(BATCH, 16), dim3(256), 0, stream>>>(b1, colpart);
  colmean_finish_kernel<<<dim3(16), dim3(256), 0, stream>>>(colpart, colmu);
  sub_colmean_kernel<<<dim3(MROWS), dim3(256), 0, stream>>>(b1, colmu, enc_out);

  // ----- decoder -----
  for (int l = 0; l < 2; ++l) {
    size_t wOff = (size_t)l * WSLOT, bOff = (size_t)l * DMODEL;
    run_attn(dec_out, dec_out, dec_out,
             dec_sWq + wOff, dec_sbq + bOff, dec_sWk + wOff, dec_sbk + bOff,
             wt_dec_sWv + wOff, dec_sbv + bOff, wt_dec_sWo + wOff, dec_sbo + bOff,
             b1, b2, b3, sc, stream);                                   // b3 = self-attn out
    launch_add_decomp(dec_out, b3, b2, tsum, 1, stream);                // x = b2, tsum = t1
    // dec_out is dead until end of loop body — reuse as cross-attn temp/out.
    run_attn(b2, enc_out, enc_out,
             dec_cWq + wOff, dec_cbq + bOff, dec_cWk + wOff, dec_cbk + bOff,
             wt_dec_cWv + wOff, dec_cbv + bOff, wt_dec_cWo + wOff, dec_cbo + bOff,
             b1, b3, dec_out, sc, stream);                              // dec_out = cross out
    launch_add_decomp(b2, dec_out, b3, tsum, 2, stream);                // x = b3, tsum += t2
    launch_gemm_bf16(b3, wt_dec_c1 + wOff, nullptr, b1, 1, stream);     // b1 = gelu(x@c1)
    launch_gemm_bf16(b1, wt_dec_c2 + wOff, nullptr, b2, 0, stream);     // b2 = y
    launch_add_decomp(b3, b2, dec_out, tsum, 2, stream);                // dec_out, tsum += t3
    trend_conv_kernel<<<dim3(MROWS), dim3(64), 0, stream>>>(
        tsum, dec_trendW + (size_t)l * 3 * DMODEL * 7, trend_acc);
  }
  layernorm_kernel<<<dim3(MROWS), dim3(256), 0, stream>>>(dec_out, dec_nw, dec_nb, b1);
  colsum_kernel<<<dim3(BATCH, 16), dim3(256), 0, stream>>>(b1, colpart);
  colmean_finish_kernel<<<dim3(16), dim3(256), 0, stream>>>(colpart, colmu);
  sub_colmean_kernel<<<dim3(MROWS), dim3(256), 0, stream>>>(b1, colmu, b2);
  final_proj_kernel<<<dim3(BATCH * 1024), dim3(64), 0, stream>>>(
      b2, proj_W, proj_b, trend_acc, (float*)d_out);
}